// Round 13
// baseline (855.957 us; speedup 1.0000x reference)
//
#include <hip/hip_runtime.h>

// SchNet, multi-kernel bf16-MFMA pipeline, PAIR-SYMMETRY edition.
// h2(i,j)=h2(j,i): pair columns reparametrized by cyclic offset o; columns
// o=1..31 cover each unordered pair once; o=32 half-column (nt 0,1, same-lane
// j-slot). Filter GEMM/tanh/exp2 work HALVED (64 -> 32.5 columns/layer).
// A(b,half): half=0 -> o 1..16, half=1 -> o 17..32. Per column:
//   rbf -> h1=tanh(Wf1@rbf) -> h2-in-reg; v[p]+=h*Xl[j] in REGISTERS
//   (p-rows lane-fixed); v[j]+=h*Xl[p] shipped via __shfl rotation by o in
//   the 16-lane group + carry-rotated static slot add. Partial v (f32) ->
//   gVp[half][b]. B sums the 2 partials.
// d_ws: [0,256K) wfrags; [256K,+8M) gX f32; [+,+4M) gXl bf16; [+,+16M) gVp f32.

typedef __attribute__((ext_vector_type(8))) __bf16 bf16x8;
typedef __attribute__((ext_vector_type(4))) __bf16 bf16x4;
typedef __attribute__((ext_vector_type(4))) float  f32x4;

#define WS_X  262144
#define WS_XL 8650752
#define WS_VP 12845056

__device__ __forceinline__ int swz(int row, int byteoff) {
    return row * 128 + (byteoff ^ ((row & 7) << 4));
}

__device__ __forceinline__ float fexp2(float x) { return __builtin_amdgcn_exp2f(x); }

__device__ __forceinline__ float tanh_fast(float x) {
    float t = fexp2(2.88539008f * x);
    return fmaf(-2.0f, __builtin_amdgcn_rcpf(t + 1.0f), 1.0f);
}

struct AFrag { bf16x8 a0h, a1h, a0l, a1l; };

__device__ __forceinline__ AFrag load_afrag(const char* wsW, int mat, int wv, int lane) {
    const char* p = wsW + mat * 16384 + wv * 2048 + lane * 32;
    AFrag f;
    f.a0h = *(const bf16x8*)(p);
    f.a1h = *(const bf16x8*)(p + 16);
    f.a0l = *(const bf16x8*)(p + 8192);
    f.a1l = *(const bf16x8*)(p + 8192 + 16);
    return f;
}

// D[m=f_out][n=row] = A(split) * B. bv = per-thread bias fragment.
// EPI 0: +bias store; 1: +bias tanh store; 2: raw acc -> ret.
template <int EPI, bool BSPLIT>
__device__ __forceinline__ void gemm64(const AFrag& A, const char* Bhi, const char* Blo,
                                       const f32x4 bv, char* Out,
                                       int lane, int wv, f32x4* ret) {
    const int l15 = lane & 15, q = lane >> 4;
    f32x4 acc[4];
#pragma unroll
    for (int nt = 0; nt < 4; ++nt) {
        const int n = 16 * nt + l15;
        const bf16x8 b0h = *(const bf16x8*)(Bhi + swz(n, 16 * q));
        const bf16x8 b1h = *(const bf16x8*)(Bhi + swz(n, 64 + 16 * q));
        f32x4 c = {0.f, 0.f, 0.f, 0.f};
        c = __builtin_amdgcn_mfma_f32_16x16x32_bf16(A.a0h, b0h, c, 0, 0, 0);
        c = __builtin_amdgcn_mfma_f32_16x16x32_bf16(A.a1h, b1h, c, 0, 0, 0);
        c = __builtin_amdgcn_mfma_f32_16x16x32_bf16(A.a0l, b0h, c, 0, 0, 0);
        c = __builtin_amdgcn_mfma_f32_16x16x32_bf16(A.a1l, b1h, c, 0, 0, 0);
        if (BSPLIT) {
            const bf16x8 b0l = *(const bf16x8*)(Blo + swz(n, 16 * q));
            const bf16x8 b1l = *(const bf16x8*)(Blo + swz(n, 64 + 16 * q));
            c = __builtin_amdgcn_mfma_f32_16x16x32_bf16(A.a0h, b0l, c, 0, 0, 0);
            c = __builtin_amdgcn_mfma_f32_16x16x32_bf16(A.a1h, b1l, c, 0, 0, 0);
        }
        acc[nt] = c;
    }
    if (EPI == 2) {
#pragma unroll
        for (int nt = 0; nt < 4; ++nt) ret[nt] = acc[nt];
        return;
    }
#pragma unroll
    for (int nt = 0; nt < 4; ++nt) {
        const int n = 16 * nt + l15;
        bf16x4 oh;
#pragma unroll
        for (int r = 0; r < 4; ++r) {
            float v = acc[nt][r] + bv[r];
            if (EPI == 1) v = tanh_fast(v);
            oh[r] = (__bf16)v;
        }
        *(bf16x4*)(Out + swz(n, 32 * wv + 8 * q)) = oh;
    }
}

__global__ void prep_weights(const float* __restrict__ Wx, const float* __restrict__ Wf1,
                             const float* __restrict__ Wf2, const float* __restrict__ Wv1,
                             const float* __restrict__ Wv2, const float* __restrict__ W1,
                             char* __restrict__ ws) {
    const int m = blockIdx.x;
    const int tid = threadIdx.x;
    const int wv = tid >> 6, lane = tid & 63;
    const int l15 = lane & 15, q = lane >> 4;
    const int m_row = 16 * wv + l15;
    const float* src;
    int wcols;
    if (m < 15) {
        const int t = m / 5, s = m % 5;
        src = (s == 0 ? Wx : s == 1 ? Wf1 : s == 2 ? Wf2 : s == 3 ? Wv1 : Wv2) + t * 4096;
        wcols = 64;
    } else {
        src = W1;
        wcols = 32;
    }
    char* base = ws + m * 16384 + wv * 2048 + lane * 32;
#pragma unroll
    for (int kc = 0; kc < 2; ++kc) {
        bf16x8 hi, lo;
#pragma unroll
        for (int e = 0; e < 8; ++e) {
            const int k = 32 * kc + 8 * q + e;
            float val = (m_row < wcols) ? src[k * wcols + m_row] : 0.0f;
            __bf16 h = (__bf16)val;
            hi[e] = h;
            lo[e] = (__bf16)(val - (float)h);
        }
        *(bf16x8*)(base + kc * 16) = hi;
        *(bf16x8*)(base + 8192 + kc * 16) = lo;
    }
}

// init: X0 (fp32 -> gX) and Xl0 = Wx0 @ X0 + bx0 -> gXl (bf16, natural layout).
__global__ __launch_bounds__(256, 2) void schnet_init(
    const float* __restrict__ v1g, const float* __restrict__ v2g,
    const float* __restrict__ bx,  const char* __restrict__ wsW,
    float* __restrict__ gX, __bf16* __restrict__ gXl) {
    extern __shared__ char smem[];
    char* bX   = smem;          // 8192 X hi
    char* bXlo = smem + 8192;   // 8192 X lo

    const int tid = threadIdx.x;
    const int lane = tid & 63, wv = tid >> 6;
    const int l15 = lane & 15, q = lane >> 4;
    const int b = blockIdx.x;

    {
        const f32x4 a1v = *(const f32x4*)(v1g + 16 * wv + 4 * q);
        const f32x4 a2v = *(const f32x4*)(v2g + 16 * wv + 4 * q);
#pragma unroll
        for (int nt = 0; nt < 4; ++nt) {
            const bool isv1 = (nt == 0) && (l15 < 2);
            bf16x4 oh, ol;
            f32x4 m;
#pragma unroll
            for (int rr = 0; rr < 4; ++rr) {
                m[rr] = isv1 ? a1v[rr] : a2v[rr];
                __bf16 h = (__bf16)m[rr];
                oh[rr] = h;
                ol[rr] = (__bf16)(m[rr] - (float)h);
            }
            const int off = swz(16 * nt + l15, 32 * wv + 8 * q);
            *(bf16x4*)(bX + off) = oh;
            *(bf16x4*)(bXlo + off) = ol;
            *(f32x4*)(gX + b * 4096 + (16 * nt + l15) * 64 + 16 * wv + 4 * q) = m;
        }
    }
    __syncthreads();
    {
        const AFrag fWx = load_afrag(wsW, 0, wv, lane);
        const f32x4 bxv = *(const f32x4*)(bx + 16 * wv + 4 * q);
        f32x4 acc[4];
        gemm64<2, true>(fWx, bX, bXlo, bxv, nullptr, lane, wv, acc);
#pragma unroll
        for (int nt = 0; nt < 4; ++nt) {
            bf16x4 oh;
#pragma unroll
            for (int rr = 0; rr < 4; ++rr) oh[rr] = (__bf16)(acc[nt][rr] + bxv[rr]);
            *(bf16x4*)(gXl + (b * 64 + 16 * nt + l15) * 64 + 16 * wv + 4 * q) = oh;
        }
    }
}

// A: grid 1024 = (b, half). 16 offset-columns per block. 17.4KB LDS, (256,4).
__global__ __launch_bounds__(256, 4) void schnet_a(
    const float* __restrict__ r,   const float* __restrict__ cent,
    const float* __restrict__ bf1, const float* __restrict__ bf2,
    const char* __restrict__ wsW,  const __bf16* __restrict__ gXl,
    float* __restrict__ gVp, int t) {
    extern __shared__ char smem[];
    char* bA  = smem;                       // 8192  rbf
    char* bB  = smem + 8192;                // 8192  h1
    float* sPos  = (float*)(smem + 16384);  // [3][64]
    float* sCent = (float*)(smem + 17152);  // 256B -> total 17408

    const int tid = threadIdx.x;
    const int lane = tid & 63, wv = tid >> 6;
    const int l15 = lane & 15, q = lane >> 4;
    const int b = blockIdx.x >> 1, half = blockIdx.x & 1;

    if (tid < 192) sPos[(tid % 3) * 64 + tid / 3] = r[b * 192 + tid];
    if (tid < 64) sCent[tid] = cent[tid];

    const AFrag fWf1 = load_afrag(wsW, t * 5 + 1, wv, lane);
    const AFrag fWf2 = load_afrag(wsW, t * 5 + 2, wv, lane);
    const f32x4 bf1v = *(const f32x4*)(bf1 + t * 64 + 16 * wv + 4 * q);
    const f32x4 bf2v = *(const f32x4*)(bf2 + t * 64 + 16 * wv + 4 * q);

    // Xl fragment for own p-rows (L2-resident global)
    float xlf[4][4];
#pragma unroll
    for (int nt = 0; nt < 4; ++nt) {
        const bf16x4 xl = *(const bf16x4*)(gXl + (b * 64 + 16 * nt + l15) * 64 +
                                           16 * wv + 4 * q);
#pragma unroll
        for (int r2 = 0; r2 < 4; ++r2) xlf[nt][r2] = (float)xl[r2];
    }
    // per-lane v accumulator for rows p = 16*nt + l15 (C-fragment layout)
    f32x4 vacc[4];
#pragma unroll
    for (int nt = 0; nt < 4; ++nt) vacc[nt] = f32x4{0.f, 0.f, 0.f, 0.f};
    __syncthreads();

    const float pjx = sPos[lane], pjy = sPos[64 + lane], pjz = sPos[128 + lane];
    const float* ccp = sCent + wv * 16;
    const int o0 = 1 + half * 16;

    // rbf for offset column o: row p=lane pairs with atom (p+o)&63
#define RBF_COL(O)                                                        \
    {                                                                     \
        const int jj = (lane + (O)) & 63;                                 \
        const float dx = pjx - sPos[jj];                                  \
        const float dy = pjy - sPos[64 + jj];                             \
        const float dz = pjz - sPos[128 + jj];                            \
        const float d = __builtin_amdgcn_sqrtf(dx * dx + dy * dy + dz * dz); \
        bf16x8 h0, h1v;                                                   \
        _Pragma("unroll")                                                 \
        for (int e = 0; e < 8; ++e) {                                     \
            float x0 = d - ccp[e];                                        \
            float x1 = d - ccp[8 + e];                                    \
            h0[e]  = (__bf16)fexp2(-14.4269504f * x0 * x0);               \
            h1v[e] = (__bf16)fexp2(-14.4269504f * x1 * x1);               \
        }                                                                 \
        *(bf16x8*)(bA + swz(lane, 32 * wv)) = h0;                         \
        *(bf16x8*)(bA + swz(lane, 32 * wv + 16)) = h1v;                   \
    }

    RBF_COL(o0);
    __syncthreads();

    for (int oc = 0; oc < 16; ++oc) {
        const int o = o0 + oc;
        // phase 1: h1 = tanh(Wf1 @ rbf + bf1) -> bB
        gemm64<1, false>(fWf1, bA, nullptr, bf1v, bB, lane, wv, nullptr);
        __syncthreads();
        // phase 2: h2 in-reg; both-side scatter (regs + shfl)  ||  rbf(o+1)
        {
            bf16x4 xjl[4];
            if (o != 32) {
#pragma unroll
                for (int nt = 0; nt < 4; ++nt) {
                    const int j = (16 * nt + l15 + o) & 63;
                    xjl[nt] = *(const bf16x4*)(gXl + (b * 64 + j) * 64 +
                                               16 * wv + 4 * q);
                }
            }
            f32x4 ret[4];
            gemm64<2, false>(fWf2, bB, nullptr, bf2v, nullptr, lane, wv, ret);
            if (o != 32) {
                f32x4 prod[4];
#pragma unroll
                for (int nt = 0; nt < 4; ++nt) {
#pragma unroll
                    for (int r2 = 0; r2 < 4; ++r2) {
                        const float hv = tanh_fast(ret[nt][r2] + bf2v[r2]);
                        vacc[nt][r2] = fmaf(hv, (float)xjl[nt][r2], vacc[nt][r2]);
                        prod[nt][r2] = hv * xlf[nt][r2];
                    }
                }
                // ship prod to the lane owning row j: rotate by o in 16-group
                const int srcLane = (lane & 48) | ((l15 - o) & 15);
                f32x4 rx[4];
#pragma unroll
                for (int nt = 0; nt < 4; ++nt)
#pragma unroll
                    for (int r2 = 0; r2 < 4; ++r2)
                        rx[nt][r2] = __shfl(prod[nt][r2], srcLane, 64);
                const int carry = (((l15 - o) & 15) + o) >> 4;
                if (carry == 0) {
                    vacc[0] += rx[0]; vacc[1] += rx[1];
                    vacc[2] += rx[2]; vacc[3] += rx[3];
                } else if (carry == 1) {
                    vacc[1] += rx[0]; vacc[2] += rx[1];
                    vacc[3] += rx[2]; vacc[0] += rx[3];
                } else {
                    vacc[2] += rx[0]; vacc[3] += rx[1];
                    vacc[0] += rx[2]; vacc[1] += rx[3];
                }
            } else {
                // o==32: pairs (p, p+32) for p<32 (nt 0,1); partner row is
                // this lane's own slot nt+2 and its Xl is xlf[nt+2].
#pragma unroll
                for (int nt = 0; nt < 2; ++nt) {
#pragma unroll
                    for (int r2 = 0; r2 < 4; ++r2) {
                        const float hv = tanh_fast(ret[nt][r2] + bf2v[r2]);
                        vacc[nt][r2]     = fmaf(hv, xlf[nt + 2][r2], vacc[nt][r2]);
                        vacc[nt + 2][r2] = fmaf(hv, xlf[nt][r2], vacc[nt + 2][r2]);
                    }
                }
            }
        }
        if (oc < 15) RBF_COL(o + 1);
        __syncthreads();
    }

    // write partial v (registers) -> gVp[half][b]  (f32, natural layout)
    {
        float* dst = gVp + (half * 512 + b) * 4096;
#pragma unroll
        for (int nt = 0; nt < 4; ++nt)
            *(f32x4*)(dst + (16 * nt + l15) * 64 + 16 * wv + 4 * q) = vacc[nt];
    }
#undef RBF_COL
}

// B: grid 512. v = sum of partials -> u -> X update; t<2: Xl(t+1); t==2: head.
__global__ __launch_bounds__(256, 2) void schnet_b(
    const float* __restrict__ bv1, const float* __restrict__ bv2,
    const float* __restrict__ bx,  const float* __restrict__ b1,
    const float* __restrict__ W2,  const float* __restrict__ b2,
    const char* __restrict__ wsW,  float* __restrict__ gX,
    const float* __restrict__ gVp, __bf16* __restrict__ gXl,
    float* __restrict__ out, int t) {
    extern __shared__ char smem[];
    char* bV   = smem;                      // 8192 v bf16
    char* bB   = smem + 8192;               // 8192 u bf16
    char* bX   = smem + 16384;              // 8192 X hi
    char* bXlo = smem + 24576;              // 8192 X lo
    float* sRed = (float*)(smem + 32768);   // [2][64]
    float* sW2v = (float*)(smem + 33280);   // 128B -> total 33408

    const int tid = threadIdx.x;
    const int lane = tid & 63, wv = tid >> 6;
    const int l15 = lane & 15, q = lane >> 4;
    const int b = blockIdx.x;

    if (tid < 32) sW2v[tid] = W2[tid];

    {   // stage v = gVp[0][b] + gVp[1][b] -> bV (bf16, swizzled)
        const int a2 = tid >> 2, f0 = (tid & 3) << 4;
        const float* s0 = gVp + b * 4096 + a2 * 64 + f0;
        const float* s1 = gVp + (512 + b) * 4096 + a2 * 64 + f0;
#pragma unroll
        for (int c = 0; c < 4; ++c) {
            const f32x4 va = *(const f32x4*)(s0 + 4 * c);
            const f32x4 vb = *(const f32x4*)(s1 + 4 * c);
            bf16x4 o4;
#pragma unroll
            for (int r2 = 0; r2 < 4; ++r2) o4[r2] = (__bf16)(va[r2] + vb[r2]);
            *(bf16x4*)(bV + swz(a2, 2 * (f0 + 4 * c))) = o4;
        }
    }
    __syncthreads();
    {   // u = tanh(Wv1 @ v + bv1) -> bB
        const AFrag fWv1 = load_afrag(wsW, t * 5 + 3, wv, lane);
        const f32x4 bv1v = *(const f32x4*)(bv1 + t * 64 + 16 * wv + 4 * q);
        gemm64<1, false>(fWv1, bV, nullptr, bv1v, bB, lane, wv, nullptr);
    }
    __syncthreads();
    // X += Wv2 @ u + bv2 (global fp32 master), materialize hi/lo planes
    f32x4 master[4];
    {
        const AFrag fWv2 = load_afrag(wsW, t * 5 + 4, wv, lane);
        f32x4 ret[4];
        gemm64<2, false>(fWv2, bB, nullptr, f32x4{0.f, 0.f, 0.f, 0.f}, nullptr,
                         lane, wv, ret);
        const f32x4 bvec = *(const f32x4*)(bv2 + t * 64 + 16 * wv + 4 * q);
#pragma unroll
        for (int nt = 0; nt < 4; ++nt) {
            float* px = gX + b * 4096 + (16 * nt + l15) * 64 + 16 * wv + 4 * q;
            f32x4 m = *(const f32x4*)px;
#pragma unroll
            for (int rr = 0; rr < 4; ++rr) m[rr] += ret[nt][rr] + bvec[rr];
            *(f32x4*)px = m;
            master[nt] = m;
            bf16x4 oh, ol;
#pragma unroll
            for (int rr = 0; rr < 4; ++rr) {
                __bf16 h = (__bf16)m[rr];
                oh[rr] = h;
                ol[rr] = (__bf16)(m[rr] - (float)h);
            }
            const int off = swz(16 * nt + l15, 32 * wv + 8 * q);
            *(bf16x4*)(bX + off) = oh;
            *(bf16x4*)(bXlo + off) = ol;
        }
    }
    __syncthreads();

    if (t < 2) {
        // Xl(t+1) = Wx(t+1) @ X + bx(t+1) -> gXl (natural bf16)
        const AFrag fWxn = load_afrag(wsW, (t + 1) * 5 + 0, wv, lane);
        const f32x4 bxv = *(const f32x4*)(bx + (t + 1) * 64 + 16 * wv + 4 * q);
        f32x4 acc[4];
        gemm64<2, true>(fWxn, bX, bXlo, bxv, nullptr, lane, wv, acc);
#pragma unroll
        for (int nt = 0; nt < 4; ++nt) {
            bf16x4 oh;
#pragma unroll
            for (int rr = 0; rr < 4; ++rr) oh[rr] = (__bf16)(acc[nt][rr] + bxv[rr]);
            *(bf16x4*)(gXl + (b * 64 + 16 * nt + l15) * 64 + 16 * wv + 4 * q) = oh;
        }
    } else {
        if (wv < 2) {
            const AFrag fW1 = load_afrag(wsW, 15, wv, lane);
            const f32x4 b1v = *(const f32x4*)(b1 + 16 * wv + 4 * q);
            const f32x4 w2v = *(const f32x4*)(sW2v + 16 * wv + 4 * q);
#pragma unroll
            for (int nt = 0; nt < 4; ++nt) {
                const int n = 16 * nt + l15;
                const bf16x8 b0h = *(const bf16x8*)(bX + swz(n, 16 * q));
                const bf16x8 b1h = *(const bf16x8*)(bX + swz(n, 64 + 16 * q));
                const bf16x8 b0l = *(const bf16x8*)(bXlo + swz(n, 16 * q));
                const bf16x8 b1l = *(const bf16x8*)(bXlo + swz(n, 64 + 16 * q));
                f32x4 c = {0.f, 0.f, 0.f, 0.f};
                c = __builtin_amdgcn_mfma_f32_16x16x32_bf16(fW1.a0h, b0h, c, 0, 0, 0);
                c = __builtin_amdgcn_mfma_f32_16x16x32_bf16(fW1.a1h, b1h, c, 0, 0, 0);
                c = __builtin_amdgcn_mfma_f32_16x16x32_bf16(fW1.a0h, b0l, c, 0, 0, 0);
                c = __builtin_amdgcn_mfma_f32_16x16x32_bf16(fW1.a1h, b1l, c, 0, 0, 0);
                c = __builtin_amdgcn_mfma_f32_16x16x32_bf16(fW1.a0l, b0h, c, 0, 0, 0);
                c = __builtin_amdgcn_mfma_f32_16x16x32_bf16(fW1.a1l, b1h, c, 0, 0, 0);
                float p = 0.f;
#pragma unroll
                for (int rr = 0; rr < 4; ++rr)
                    p = fmaf(tanh_fast(c[rr] + b1v[rr]), w2v[rr], p);
                p += __shfl_xor(p, 16);
                p += __shfl_xor(p, 32);
                if (q == 0) sRed[wv * 64 + nt * 16 + l15] = p;
            }
        }
        __syncthreads();
        if (tid < 64) {
            float s = sRed[tid] + sRed[64 + tid];
#pragma unroll
            for (int off = 1; off < 64; off <<= 1) s += __shfl_xor(s, off);
            if (tid == 0) out[b] = s + 64.0f * b2[0];
        }
    }
}

extern "C" void kernel_launch(void* const* d_in, const int* in_sizes, int n_in,
                              void* d_out, int out_size, void* d_ws, size_t ws_size,
                              hipStream_t stream) {
    const float* r    = (const float*)d_in[0];
    const float* v1   = (const float*)d_in[1];
    const float* v2   = (const float*)d_in[2];
    const float* cent = (const float*)d_in[3];
    const float* Wx   = (const float*)d_in[4];
    const float* bx   = (const float*)d_in[5];
    const float* Wf1  = (const float*)d_in[6];
    const float* bf1  = (const float*)d_in[7];
    const float* Wf2  = (const float*)d_in[8];
    const float* bf2  = (const float*)d_in[9];
    const float* Wv1  = (const float*)d_in[10];
    const float* bv1  = (const float*)d_in[11];
    const float* Wv2  = (const float*)d_in[12];
    const float* bv2  = (const float*)d_in[13];
    const float* W1   = (const float*)d_in[14];
    const float* b1   = (const float*)d_in[15];
    const float* W2   = (const float*)d_in[16];
    const float* b2   = (const float*)d_in[17];
    char* ws = (char*)d_ws;
    float*  gX  = (float*)(ws + WS_X);
    __bf16* gXl = (__bf16*)(ws + WS_XL);
    float*  gVp = (float*)(ws + WS_VP);

    prep_weights<<<16, 256, 0, stream>>>(Wx, Wf1, Wf2, Wv1, Wv2, W1, ws);
    schnet_init<<<512, 256, 16384, stream>>>(v1, v2, bx, ws, gX, gXl);

    (void)hipFuncSetAttribute((const void*)schnet_a,
                              hipFuncAttributeMaxDynamicSharedMemorySize, 17408);
    (void)hipFuncSetAttribute((const void*)schnet_b,
                              hipFuncAttributeMaxDynamicSharedMemorySize, 33408);
    for (int t = 0; t < 3; ++t) {
        schnet_a<<<1024, 256, 17408, stream>>>(r, cent, bf1, bf2, ws, gXl, gVp, t);
        schnet_b<<<512, 256, 33408, stream>>>(bv1, bv2, bx, b1, W2, b2, ws, gX,
                                              gVp, gXl, (float*)d_out, t);
    }
}

// Round 14
// 391.612 us; speedup vs baseline: 2.1857x; 2.1857x over previous
//
#include <hip/hip_runtime.h>

// SchNet, multi-kernel bf16-MFMA pipeline, PAIR-SYMMETRY edition v2.
// h2(i,j)=h2(j,i): pair columns reparametrized by cyclic offset o; columns
// o=1..31 cover each unordered pair once; o=32 half-column. Filter work HALVED.
// R13 lesson: batched epilogue (prod[4][4]+rx[4][4]+xjl[4] live at once) =
// ~160-reg live set -> scratch spills (WRITE 330MB). v2: per-nt epilogue,
// transients <=10 regs; own-row Xl kept bf16 (8 regs). Live ~105 < 128 cap.
// A(b,half): half=0 -> o 1..16, half=1 -> o 17..32. Per column:
//   rbf -> h1=tanh(Wf1@rbf) -> h2-in-reg; v[p]+=h*Xl[j] in regs;
//   v[j]+=h*Xl[p] via __shfl rotation + carry-rotated slot add.
// Partial v (f32) -> gVp[half][b]; B sums the 2 partials.
// d_ws: [0,256K) wfrags; [256K,+8M) gX f32; [+,+4M) gXl bf16; [+,+16M) gVp f32.

typedef __attribute__((ext_vector_type(8))) __bf16 bf16x8;
typedef __attribute__((ext_vector_type(4))) __bf16 bf16x4;
typedef __attribute__((ext_vector_type(4))) float  f32x4;

#define WS_X  262144
#define WS_XL 8650752
#define WS_VP 12845056

__device__ __forceinline__ int swz(int row, int byteoff) {
    return row * 128 + (byteoff ^ ((row & 7) << 4));
}

__device__ __forceinline__ float fexp2(float x) { return __builtin_amdgcn_exp2f(x); }

__device__ __forceinline__ float tanh_fast(float x) {
    float t = fexp2(2.88539008f * x);
    return fmaf(-2.0f, __builtin_amdgcn_rcpf(t + 1.0f), 1.0f);
}

struct AFrag { bf16x8 a0h, a1h, a0l, a1l; };

__device__ __forceinline__ AFrag load_afrag(const char* wsW, int mat, int wv, int lane) {
    const char* p = wsW + mat * 16384 + wv * 2048 + lane * 32;
    AFrag f;
    f.a0h = *(const bf16x8*)(p);
    f.a1h = *(const bf16x8*)(p + 16);
    f.a0l = *(const bf16x8*)(p + 8192);
    f.a1l = *(const bf16x8*)(p + 8192 + 16);
    return f;
}

// D[m=f_out][n=row] = A(split) * B. bv = per-thread bias fragment.
// EPI 0: +bias store; 1: +bias tanh store; 2: raw acc -> ret.
template <int EPI, bool BSPLIT>
__device__ __forceinline__ void gemm64(const AFrag& A, const char* Bhi, const char* Blo,
                                       const f32x4 bv, char* Out,
                                       int lane, int wv, f32x4* ret) {
    const int l15 = lane & 15, q = lane >> 4;
    f32x4 acc[4];
#pragma unroll
    for (int nt = 0; nt < 4; ++nt) {
        const int n = 16 * nt + l15;
        const bf16x8 b0h = *(const bf16x8*)(Bhi + swz(n, 16 * q));
        const bf16x8 b1h = *(const bf16x8*)(Bhi + swz(n, 64 + 16 * q));
        f32x4 c = {0.f, 0.f, 0.f, 0.f};
        c = __builtin_amdgcn_mfma_f32_16x16x32_bf16(A.a0h, b0h, c, 0, 0, 0);
        c = __builtin_amdgcn_mfma_f32_16x16x32_bf16(A.a1h, b1h, c, 0, 0, 0);
        c = __builtin_amdgcn_mfma_f32_16x16x32_bf16(A.a0l, b0h, c, 0, 0, 0);
        c = __builtin_amdgcn_mfma_f32_16x16x32_bf16(A.a1l, b1h, c, 0, 0, 0);
        if (BSPLIT) {
            const bf16x8 b0l = *(const bf16x8*)(Blo + swz(n, 16 * q));
            const bf16x8 b1l = *(const bf16x8*)(Blo + swz(n, 64 + 16 * q));
            c = __builtin_amdgcn_mfma_f32_16x16x32_bf16(A.a0h, b0l, c, 0, 0, 0);
            c = __builtin_amdgcn_mfma_f32_16x16x32_bf16(A.a1h, b1l, c, 0, 0, 0);
        }
        acc[nt] = c;
    }
    if (EPI == 2) {
#pragma unroll
        for (int nt = 0; nt < 4; ++nt) ret[nt] = acc[nt];
        return;
    }
#pragma unroll
    for (int nt = 0; nt < 4; ++nt) {
        const int n = 16 * nt + l15;
        bf16x4 oh;
#pragma unroll
        for (int r = 0; r < 4; ++r) {
            float v = acc[nt][r] + bv[r];
            if (EPI == 1) v = tanh_fast(v);
            oh[r] = (__bf16)v;
        }
        *(bf16x4*)(Out + swz(n, 32 * wv + 8 * q)) = oh;
    }
}

__global__ void prep_weights(const float* __restrict__ Wx, const float* __restrict__ Wf1,
                             const float* __restrict__ Wf2, const float* __restrict__ Wv1,
                             const float* __restrict__ Wv2, const float* __restrict__ W1,
                             char* __restrict__ ws) {
    const int m = blockIdx.x;
    const int tid = threadIdx.x;
    const int wv = tid >> 6, lane = tid & 63;
    const int l15 = lane & 15, q = lane >> 4;
    const int m_row = 16 * wv + l15;
    const float* src;
    int wcols;
    if (m < 15) {
        const int t = m / 5, s = m % 5;
        src = (s == 0 ? Wx : s == 1 ? Wf1 : s == 2 ? Wf2 : s == 3 ? Wv1 : Wv2) + t * 4096;
        wcols = 64;
    } else {
        src = W1;
        wcols = 32;
    }
    char* base = ws + m * 16384 + wv * 2048 + lane * 32;
#pragma unroll
    for (int kc = 0; kc < 2; ++kc) {
        bf16x8 hi, lo;
#pragma unroll
        for (int e = 0; e < 8; ++e) {
            const int k = 32 * kc + 8 * q + e;
            float val = (m_row < wcols) ? src[k * wcols + m_row] : 0.0f;
            __bf16 h = (__bf16)val;
            hi[e] = h;
            lo[e] = (__bf16)(val - (float)h);
        }
        *(bf16x8*)(base + kc * 16) = hi;
        *(bf16x8*)(base + 8192 + kc * 16) = lo;
    }
}

// init: X0 (fp32 -> gX) and Xl0 = Wx0 @ X0 + bx0 -> gXl (bf16, natural layout).
__global__ __launch_bounds__(256, 2) void schnet_init(
    const float* __restrict__ v1g, const float* __restrict__ v2g,
    const float* __restrict__ bx,  const char* __restrict__ wsW,
    float* __restrict__ gX, __bf16* __restrict__ gXl) {
    extern __shared__ char smem[];
    char* bX   = smem;          // 8192 X hi
    char* bXlo = smem + 8192;   // 8192 X lo

    const int tid = threadIdx.x;
    const int lane = tid & 63, wv = tid >> 6;
    const int l15 = lane & 15, q = lane >> 4;
    const int b = blockIdx.x;

    {
        const f32x4 a1v = *(const f32x4*)(v1g + 16 * wv + 4 * q);
        const f32x4 a2v = *(const f32x4*)(v2g + 16 * wv + 4 * q);
#pragma unroll
        for (int nt = 0; nt < 4; ++nt) {
            const bool isv1 = (nt == 0) && (l15 < 2);
            bf16x4 oh, ol;
            f32x4 m;
#pragma unroll
            for (int rr = 0; rr < 4; ++rr) {
                m[rr] = isv1 ? a1v[rr] : a2v[rr];
                __bf16 h = (__bf16)m[rr];
                oh[rr] = h;
                ol[rr] = (__bf16)(m[rr] - (float)h);
            }
            const int off = swz(16 * nt + l15, 32 * wv + 8 * q);
            *(bf16x4*)(bX + off) = oh;
            *(bf16x4*)(bXlo + off) = ol;
            *(f32x4*)(gX + b * 4096 + (16 * nt + l15) * 64 + 16 * wv + 4 * q) = m;
        }
    }
    __syncthreads();
    {
        const AFrag fWx = load_afrag(wsW, 0, wv, lane);
        const f32x4 bxv = *(const f32x4*)(bx + 16 * wv + 4 * q);
        f32x4 acc[4];
        gemm64<2, true>(fWx, bX, bXlo, bxv, nullptr, lane, wv, acc);
#pragma unroll
        for (int nt = 0; nt < 4; ++nt) {
            bf16x4 oh;
#pragma unroll
            for (int rr = 0; rr < 4; ++rr) oh[rr] = (__bf16)(acc[nt][rr] + bxv[rr]);
            *(bf16x4*)(gXl + (b * 64 + 16 * nt + l15) * 64 + 16 * wv + 4 * q) = oh;
        }
    }
}

// A: grid 1024 = (b, half). 16 offset-columns per block. 17.4KB LDS, (256,4).
__global__ __launch_bounds__(256, 4) void schnet_a(
    const float* __restrict__ r,   const float* __restrict__ cent,
    const float* __restrict__ bf1, const float* __restrict__ bf2,
    const char* __restrict__ wsW,  const __bf16* __restrict__ gXl,
    float* __restrict__ gVp, int t) {
    extern __shared__ char smem[];
    char* bA  = smem;                       // 8192  rbf
    char* bB  = smem + 8192;                // 8192  h1
    float* sPos  = (float*)(smem + 16384);  // [3][64]
    float* sCent = (float*)(smem + 17152);  // 256B -> total 17408

    const int tid = threadIdx.x;
    const int lane = tid & 63, wv = tid >> 6;
    const int l15 = lane & 15, q = lane >> 4;
    const int b = blockIdx.x >> 1, half = blockIdx.x & 1;

    if (tid < 192) sPos[(tid % 3) * 64 + tid / 3] = r[b * 192 + tid];
    if (tid < 64) sCent[tid] = cent[tid];

    const AFrag fWf1 = load_afrag(wsW, t * 5 + 1, wv, lane);
    const AFrag fWf2 = load_afrag(wsW, t * 5 + 2, wv, lane);
    const f32x4 bf1v = *(const f32x4*)(bf1 + t * 64 + 16 * wv + 4 * q);
    const f32x4 bf2v = *(const f32x4*)(bf2 + t * 64 + 16 * wv + 4 * q);

    // Own-row Xl fragment, kept bf16 (8 regs), converted at use
    bf16x4 xlb[4];
#pragma unroll
    for (int nt = 0; nt < 4; ++nt)
        xlb[nt] = *(const bf16x4*)(gXl + (b * 64 + 16 * nt + l15) * 64 +
                                   16 * wv + 4 * q);
    // per-lane v accumulator for rows p = 16*nt + l15 (C-fragment layout)
    f32x4 vacc[4];
#pragma unroll
    for (int nt = 0; nt < 4; ++nt) vacc[nt] = f32x4{0.f, 0.f, 0.f, 0.f};
    __syncthreads();

    const float pjx = sPos[lane], pjy = sPos[64 + lane], pjz = sPos[128 + lane];
    const float* ccp = sCent + wv * 16;
    const int o0 = 1 + half * 16;

#define RBF_COL(O)                                                        \
    {                                                                     \
        const int jj = (lane + (O)) & 63;                                 \
        const float dx = pjx - sPos[jj];                                  \
        const float dy = pjy - sPos[64 + jj];                             \
        const float dz = pjz - sPos[128 + jj];                            \
        const float d = __builtin_amdgcn_sqrtf(dx * dx + dy * dy + dz * dz); \
        bf16x8 h0, h1v;                                                   \
        _Pragma("unroll")                                                 \
        for (int e = 0; e < 8; ++e) {                                     \
            float x0 = d - ccp[e];                                        \
            float x1 = d - ccp[8 + e];                                    \
            h0[e]  = (__bf16)fexp2(-14.4269504f * x0 * x0);               \
            h1v[e] = (__bf16)fexp2(-14.4269504f * x1 * x1);               \
        }                                                                 \
        *(bf16x8*)(bA + swz(lane, 32 * wv)) = h0;                         \
        *(bf16x8*)(bA + swz(lane, 32 * wv + 16)) = h1v;                   \
    }

    RBF_COL(o0);
    __syncthreads();

    for (int oc = 0; oc < 16; ++oc) {
        const int o = o0 + oc;
        // phase 1: h1 = tanh(Wf1 @ rbf + bf1) -> bB
        gemm64<1, false>(fWf1, bA, nullptr, bf1v, bB, lane, wv, nullptr);
        __syncthreads();
        // phase 2: h2 in-reg; both-side scatter, PER-NT (lean transients)
        {
            f32x4 ret[4];
            gemm64<2, false>(fWf2, bB, nullptr, bf2v, nullptr, lane, wv, ret);
            if (o != 32) {
                const int srcLane = (lane & 48) | ((l15 - o) & 15);
                const int carry = (((l15 - o) & 15) + o) >> 4;
#pragma unroll
                for (int nt = 0; nt < 4; ++nt) {
                    const int j = (16 * nt + l15 + o) & 63;
                    const bf16x4 xjl = *(const bf16x4*)(gXl + (b * 64 + j) * 64 +
                                                        16 * wv + 4 * q);
                    f32x4 prod;
#pragma unroll
                    for (int r2 = 0; r2 < 4; ++r2) {
                        const float hv = tanh_fast(ret[nt][r2] + bf2v[r2]);
                        vacc[nt][r2] = fmaf(hv, (float)xjl[r2], vacc[nt][r2]);
                        prod[r2] = hv * (float)xlb[nt][r2];
                    }
                    f32x4 rx;
#pragma unroll
                    for (int r2 = 0; r2 < 4; ++r2)
                        rx[r2] = __shfl(prod[r2], srcLane, 64);
                    if (carry == 0)      vacc[nt] += rx;
                    else if (carry == 1) vacc[(nt + 1) & 3] += rx;
                    else                 vacc[(nt + 2) & 3] += rx;
                }
            } else {
                // o==32: pairs (p, p+32), p<32 (nt 0,1); partner is own slot nt+2.
#pragma unroll
                for (int nt = 0; nt < 2; ++nt) {
#pragma unroll
                    for (int r2 = 0; r2 < 4; ++r2) {
                        const float hv = tanh_fast(ret[nt][r2] + bf2v[r2]);
                        vacc[nt][r2]     = fmaf(hv, (float)xlb[nt + 2][r2], vacc[nt][r2]);
                        vacc[nt + 2][r2] = fmaf(hv, (float)xlb[nt][r2], vacc[nt + 2][r2]);
                    }
                }
            }
        }
        if (oc < 15) RBF_COL(o + 1);
        __syncthreads();
    }

    // write partial v (registers) -> gVp[half][b]  (f32, natural layout)
    {
        float* dst = gVp + (half * 512 + b) * 4096;
#pragma unroll
        for (int nt = 0; nt < 4; ++nt)
            *(f32x4*)(dst + (16 * nt + l15) * 64 + 16 * wv + 4 * q) = vacc[nt];
    }
#undef RBF_COL
}

// B: grid 512. v = sum of partials -> u -> X update; t<2: Xl(t+1); t==2: head.
__global__ __launch_bounds__(256, 2) void schnet_b(
    const float* __restrict__ bv1, const float* __restrict__ bv2,
    const float* __restrict__ bx,  const float* __restrict__ b1,
    const float* __restrict__ W2,  const float* __restrict__ b2,
    const char* __restrict__ wsW,  float* __restrict__ gX,
    const float* __restrict__ gVp, __bf16* __restrict__ gXl,
    float* __restrict__ out, int t) {
    extern __shared__ char smem[];
    char* bV   = smem;                      // 8192 v bf16
    char* bB   = smem + 8192;               // 8192 u bf16
    char* bX   = smem + 16384;              // 8192 X hi
    char* bXlo = smem + 24576;              // 8192 X lo
    float* sRed = (float*)(smem + 32768);   // [2][64]
    float* sW2v = (float*)(smem + 33280);   // 128B -> total 33408

    const int tid = threadIdx.x;
    const int lane = tid & 63, wv = tid >> 6;
    const int l15 = lane & 15, q = lane >> 4;
    const int b = blockIdx.x;

    if (tid < 32) sW2v[tid] = W2[tid];

    {   // stage v = gVp[0][b] + gVp[1][b] -> bV (bf16, swizzled)
        const int a2 = tid >> 2, f0 = (tid & 3) << 4;
        const float* s0 = gVp + b * 4096 + a2 * 64 + f0;
        const float* s1 = gVp + (512 + b) * 4096 + a2 * 64 + f0;
#pragma unroll
        for (int c = 0; c < 4; ++c) {
            const f32x4 va = *(const f32x4*)(s0 + 4 * c);
            const f32x4 vb = *(const f32x4*)(s1 + 4 * c);
            bf16x4 o4;
#pragma unroll
            for (int r2 = 0; r2 < 4; ++r2) o4[r2] = (__bf16)(va[r2] + vb[r2]);
            *(bf16x4*)(bV + swz(a2, 2 * (f0 + 4 * c))) = o4;
        }
    }
    __syncthreads();
    {   // u = tanh(Wv1 @ v + bv1) -> bB
        const AFrag fWv1 = load_afrag(wsW, t * 5 + 3, wv, lane);
        const f32x4 bv1v = *(const f32x4*)(bv1 + t * 64 + 16 * wv + 4 * q);
        gemm64<1, false>(fWv1, bV, nullptr, bv1v, bB, lane, wv, nullptr);
    }
    __syncthreads();
    // X += Wv2 @ u + bv2 (global fp32 master), materialize hi/lo planes
    f32x4 master[4];
    {
        const AFrag fWv2 = load_afrag(wsW, t * 5 + 4, wv, lane);
        f32x4 ret[4];
        gemm64<2, false>(fWv2, bB, nullptr, f32x4{0.f, 0.f, 0.f, 0.f}, nullptr,
                         lane, wv, ret);
        const f32x4 bvec = *(const f32x4*)(bv2 + t * 64 + 16 * wv + 4 * q);
#pragma unroll
        for (int nt = 0; nt < 4; ++nt) {
            float* px = gX + b * 4096 + (16 * nt + l15) * 64 + 16 * wv + 4 * q;
            f32x4 m = *(const f32x4*)px;
#pragma unroll
            for (int rr = 0; rr < 4; ++rr) m[rr] += ret[nt][rr] + bvec[rr];
            *(f32x4*)px = m;
            master[nt] = m;
            bf16x4 oh, ol;
#pragma unroll
            for (int rr = 0; rr < 4; ++rr) {
                __bf16 h = (__bf16)m[rr];
                oh[rr] = h;
                ol[rr] = (__bf16)(m[rr] - (float)h);
            }
            const int off = swz(16 * nt + l15, 32 * wv + 8 * q);
            *(bf16x4*)(bX + off) = oh;
            *(bf16x4*)(bXlo + off) = ol;
        }
    }
    __syncthreads();

    if (t < 2) {
        // Xl(t+1) = Wx(t+1) @ X + bx(t+1) -> gXl (natural bf16)
        const AFrag fWxn = load_afrag(wsW, (t + 1) * 5 + 0, wv, lane);
        const f32x4 bxv = *(const f32x4*)(bx + (t + 1) * 64 + 16 * wv + 4 * q);
        f32x4 acc[4];
        gemm64<2, true>(fWxn, bX, bXlo, bxv, nullptr, lane, wv, acc);
#pragma unroll
        for (int nt = 0; nt < 4; ++nt) {
            bf16x4 oh;
#pragma unroll
            for (int rr = 0; rr < 4; ++rr) oh[rr] = (__bf16)(acc[nt][rr] + bxv[rr]);
            *(bf16x4*)(gXl + (b * 64 + 16 * nt + l15) * 64 + 16 * wv + 4 * q) = oh;
        }
    } else {
        if (wv < 2) {
            const AFrag fW1 = load_afrag(wsW, 15, wv, lane);
            const f32x4 b1v = *(const f32x4*)(b1 + 16 * wv + 4 * q);
            const f32x4 w2v = *(const f32x4*)(sW2v + 16 * wv + 4 * q);
#pragma unroll
            for (int nt = 0; nt < 4; ++nt) {
                const int n = 16 * nt + l15;
                const bf16x8 b0h = *(const bf16x8*)(bX + swz(n, 16 * q));
                const bf16x8 b1h = *(const bf16x8*)(bX + swz(n, 64 + 16 * q));
                const bf16x8 b0l = *(const bf16x8*)(bXlo + swz(n, 16 * q));
                const bf16x8 b1l = *(const bf16x8*)(bXlo + swz(n, 64 + 16 * q));
                f32x4 c = {0.f, 0.f, 0.f, 0.f};
                c = __builtin_amdgcn_mfma_f32_16x16x32_bf16(fW1.a0h, b0h, c, 0, 0, 0);
                c = __builtin_amdgcn_mfma_f32_16x16x32_bf16(fW1.a1h, b1h, c, 0, 0, 0);
                c = __builtin_amdgcn_mfma_f32_16x16x32_bf16(fW1.a0h, b0l, c, 0, 0, 0);
                c = __builtin_amdgcn_mfma_f32_16x16x32_bf16(fW1.a1h, b1l, c, 0, 0, 0);
                c = __builtin_amdgcn_mfma_f32_16x16x32_bf16(fW1.a0l, b0h, c, 0, 0, 0);
                c = __builtin_amdgcn_mfma_f32_16x16x32_bf16(fW1.a1l, b1h, c, 0, 0, 0);
                float p = 0.f;
#pragma unroll
                for (int rr = 0; rr < 4; ++rr)
                    p = fmaf(tanh_fast(c[rr] + b1v[rr]), w2v[rr], p);
                p += __shfl_xor(p, 16);
                p += __shfl_xor(p, 32);
                if (q == 0) sRed[wv * 64 + nt * 16 + l15] = p;
            }
        }
        __syncthreads();
        if (tid < 64) {
            float s = sRed[tid] + sRed[64 + tid];
#pragma unroll
            for (int off = 1; off < 64; off <<= 1) s += __shfl_xor(s, off);
            if (tid == 0) out[b] = s + 64.0f * b2[0];
        }
    }
}

extern "C" void kernel_launch(void* const* d_in, const int* in_sizes, int n_in,
                              void* d_out, int out_size, void* d_ws, size_t ws_size,
                              hipStream_t stream) {
    const float* r    = (const float*)d_in[0];
    const float* v1   = (const float*)d_in[1];
    const float* v2   = (const float*)d_in[2];
    const float* cent = (const float*)d_in[3];
    const float* Wx   = (const float*)d_in[4];
    const float* bx   = (const float*)d_in[5];
    const float* Wf1  = (const float*)d_in[6];
    const float* bf1  = (const float*)d_in[7];
    const float* Wf2  = (const float*)d_in[8];
    const float* bf2  = (const float*)d_in[9];
    const float* Wv1  = (const float*)d_in[10];
    const float* bv1  = (const float*)d_in[11];
    const float* Wv2  = (const float*)d_in[12];
    const float* bv2  = (const float*)d_in[13];
    const float* W1   = (const float*)d_in[14];
    const float* b1   = (const float*)d_in[15];
    const float* W2   = (const float*)d_in[16];
    const float* b2   = (const float*)d_in[17];
    char* ws = (char*)d_ws;
    float*  gX  = (float*)(ws + WS_X);
    __bf16* gXl = (__bf16*)(ws + WS_XL);
    float*  gVp = (float*)(ws + WS_VP);

    prep_weights<<<16, 256, 0, stream>>>(Wx, Wf1, Wf2, Wv1, Wv2, W1, ws);
    schnet_init<<<512, 256, 16384, stream>>>(v1, v2, bx, ws, gX, gXl);

    (void)hipFuncSetAttribute((const void*)schnet_a,
                              hipFuncAttributeMaxDynamicSharedMemorySize, 17408);
    (void)hipFuncSetAttribute((const void*)schnet_b,
                              hipFuncAttributeMaxDynamicSharedMemorySize, 33408);
    for (int t = 0; t < 3; ++t) {
        schnet_a<<<1024, 256, 17408, stream>>>(r, cent, bf1, bf2, ws, gXl, gVp, t);
        schnet_b<<<512, 256, 33408, stream>>>(bv1, bv2, bx, b1, W2, b2, ws, gX,
                                              gVp, gXl, (float*)d_out, t);
    }
}